// Round 7
// baseline (287.950 us; speedup 1.0000x reference)
//
#include <hip/hip_runtime.h>
#include <hip/hip_cooperative_groups.h>

namespace cg = cooperative_groups;

#define EPSB 1e-5f

typedef __attribute__((ext_vector_type(8))) short bf16x8;
typedef __attribute__((ext_vector_type(4))) float f32x4;

__device__ __forceinline__ unsigned short f2b(float f) {
  union { float f; unsigned u; } cv; cv.f = f;
  unsigned r = cv.u + 0x7FFFu + ((cv.u >> 16) & 1u);
  return (unsigned short)(r >> 16);
}

// ============ K_pred: cooperative {compress | conversions | borders} -> ke1 -> ke2 ==
__global__ __launch_bounds__(256) void k_pred(
    const float* __restrict__ x, const float* __restrict__ cw,
    const float* __restrict__ g1, const float* __restrict__ b1,
    const float* __restrict__ m1, const float* __restrict__ v1,
    const float* __restrict__ k1w,
    const float* __restrict__ gk, const float* __restrict__ bk,
    const float* __restrict__ mk, const float* __restrict__ vk,
    const float* __restrict__ k2w, const float* __restrict__ pw,
    unsigned short* __restrict__ comp_t, unsigned short* __restrict__ k1_t,
    float* __restrict__ kern_t,
    unsigned short* __restrict__ pwb, unsigned short* __restrict__ wt1,
    unsigned short* __restrict__ wt2) {
  __shared__ unsigned short sh[16896];     // S0: wl[ci][66] | S1: sA 16640 | S2: sA 9600
  cg::grid_group grid = cg::this_grid();
  int bid = blockIdx.x, t = threadIdx.x;

  // ---- S0a: stage compress weights transposed [ci][co], stride 66 (aligned u32) ----
  for (int f = t; f < 16384; f += 256) {
    int co = f >> 8, ci = f & 255;
    sh[ci * 66 + co] = f2b(cw[f]);
  }
  __syncthreads();
  // ---- S0b: compress (2 co x 2 px per item), grid-stride over 73728 ----
  for (int it = bid * 256 + t; it < 73728; it += 65536) {
    int co2 = (it & 31) * 2;
    int pg = it >> 5;
    int n = pg / 1152;
    int pix0 = (pg % 1152) * 2;
    const float* xp = x + (size_t)n * 256 * 2304 + pix0;
    float a00 = 0.f, a01 = 0.f, a10 = 0.f, a11 = 0.f;
    for (int ci = 0; ci < 256; ++ci) {
      float2 xv = *(const float2*)(xp + (size_t)ci * 2304);
      unsigned pr = *(const unsigned*)&sh[ci * 66 + co2];
      union { unsigned u; float f; } wa, wb;
      wa.u = pr << 16; wb.u = pr & 0xffff0000u;
      a00 = fmaf(xv.x, wa.f, a00); a01 = fmaf(xv.y, wa.f, a01);
      a10 = fmaf(xv.x, wb.f, a10); a11 = fmaf(xv.y, wb.f, a11);
    }
    float iv0 = g1[co2] / sqrtf(v1[co2] + EPSB);
    float iv1 = g1[co2 + 1] / sqrtf(v1[co2 + 1] + EPSB);
    float c0b = b1[co2] - m1[co2] * iv0;
    float c1b = b1[co2 + 1] - m1[co2 + 1] * iv1;
    float o00 = fmaxf(fmaf(a00, iv0, c0b), 0.f), o01 = fmaxf(fmaf(a01, iv0, c0b), 0.f);
    float o10 = fmaxf(fmaf(a10, iv1, c1b), 0.f), o11 = fmaxf(fmaf(a11, iv1, c1b), 0.f);
    int r = pix0 / 48, c = pix0 % 48;
    unsigned short* ob = comp_t + ((size_t)n * 2704 + (r + 2) * 52 + (c + 2)) * 64 + co2;
    *(unsigned*)&ob[0]  = (unsigned)f2b(o00) | ((unsigned)f2b(o10) << 16);
    *(unsigned*)&ob[64] = (unsigned)f2b(o01) | ((unsigned)f2b(o11) << 16);
  }
  // ---- S0c: weight conversions, grid-stride over 176128 ----
  for (int i2 = bid * 256 + t; i2 < 176128; i2 += 65536) {
    if (i2 < 65536) {
      pwb[i2] = f2b(pw[i2]);
    } else if (i2 < 102400) {
      int a = i2 - 65536;
      int co = a / 576, k = a % 576, tap = k >> 6, ci = k & 63;
      wt1[a] = f2b(k1w[co * 576 + ci * 9 + tap]);
    } else {
      int c2 = i2 - 102400;
      int co = c2 / 576, k = c2 % 576, tap = k >> 6, ci = k & 63;
      wt2[c2] = (co < 100) ? f2b(k2w[co * 576 + ci * 9 + tap]) : (unsigned short)0;
    }
  }
  // ---- S0d: comp_t border zeros (25600 u32) ----
  {
    int i = bid * 256 + t;
    if (i < 25600) {
      int n = i / 12800, r = i % 12800;
      int bp = r >> 5, c32 = r & 31;
      int rr, cc;
      if (bp < 104) { rr = bp / 52; cc = bp % 52; }
      else if (bp >= 296) { rr = 50 + (bp - 296) / 52; cc = (bp - 296) % 52; }
      else { int q = bp - 104; rr = 2 + (q >> 2); int c4 = q & 3; cc = (c4 < 2) ? c4 : c4 + 48; }
      ((unsigned*)comp_t)[((size_t)n * 2704 + rr * 52 + cc) * 32 + c32] = 0u;
    }
  }
  grid.sync();

  // ---- S1: ke1 (blocks 0..95, full 64 co per row) | k1_t borders (blocks 96+) ----
  if (bid < 96) {
    int n = bid / 48, y = bid % 48;
    const unsigned short* src = comp_t + ((size_t)n * 52 + y) * 52 * 64;
    for (int f = t; f < 2080; f += 256) {
      int g = f >> 3, ci0 = (f & 7) * 8;
      int cc = g % 52, rr = g / 52;
      bf16x8 vv = *(const bf16x8*)&src[(rr * 52 + cc) * 64 + ci0];
      int ba = (((rr * 52 + cc) * 64 + ci0) * 2) ^ ((cc & 7) << 4);
      *(bf16x8*)((char*)sh + ba) = vv;
    }
    __syncthreads();
    int wid = t >> 6, l = t & 63, l15 = l & 15, lg = l >> 4;
    f32x4 acc[3];
    acc[0] = acc[1] = acc[2] = (f32x4){0.f, 0.f, 0.f, 0.f};
    const unsigned short* arow = wt1 + (size_t)(wid * 16 + l15) * 576;
#pragma unroll
    for (int kbi = 0; kbi < 18; ++kbi) {
      int tap = kbi >> 1;
      int ky = tap / 3, kx = tap % 3;
      int ci0 = (kbi & 1) * 32 + lg * 8;
      bf16x8 afr = *(const bf16x8*)&arow[kbi * 32 + lg * 8];
#pragma unroll
      for (int nt = 0; nt < 3; ++nt) {
        int col = nt * 16 + l15 + 2 * kx;
        int ba = (((2 * ky * 52 + col) * 64 + ci0) * 2) ^ ((col & 7) << 4);
        bf16x8 bfr = *(const bf16x8*)((char*)sh + ba);
        acc[nt] = __builtin_amdgcn_mfma_f32_16x16x32_bf16(afr, bfr, acc[nt], 0, 0, 0);
      }
    }
    unsigned short* dst = k1_t + ((size_t)n * 50 + (y + 1)) * 50 * 64;
    int co0 = wid * 16 + lg * 4;
    float s0 = gk[co0] / sqrtf(vk[co0] + EPSB);
    float s1 = gk[co0 + 1] / sqrtf(vk[co0 + 1] + EPSB);
    float s2 = gk[co0 + 2] / sqrtf(vk[co0 + 2] + EPSB);
    float s3 = gk[co0 + 3] / sqrtf(vk[co0 + 3] + EPSB);
    float d0 = bk[co0] - mk[co0] * s0;
    float d1 = bk[co0 + 1] - mk[co0 + 1] * s1;
    float d2 = bk[co0 + 2] - mk[co0 + 2] * s2;
    float d3 = bk[co0 + 3] - mk[co0 + 3] * s3;
#pragma unroll
    for (int nt = 0; nt < 3; ++nt) {
      int px = nt * 16 + l15;
      ushort4 pk;
      pk.x = f2b(fmaxf(fmaf(acc[nt][0], s0, d0), 0.f));
      pk.y = f2b(fmaxf(fmaf(acc[nt][1], s1, d1), 0.f));
      pk.z = f2b(fmaxf(fmaf(acc[nt][2], s2, d2), 0.f));
      pk.w = f2b(fmaxf(fmaf(acc[nt][3], s3, d3), 0.f));
      *(ushort4*)&dst[(px + 1) * 64 + co0] = pk;
    }
  } else {
    int j = (bid - 96) * 256 + t;
    if (j < 12544) {
      int n = j / 6272, r = j % 6272;
      int bp = r >> 5, c32 = r & 31;
      int rr, cc;
      if (bp < 50) { rr = 0; cc = bp; }
      else if (bp >= 146) { rr = 49; cc = bp - 146; }
      else { int q = bp - 50; rr = 1 + (q >> 1); cc = (q & 1) * 49; }
      ((unsigned*)k1_t)[((size_t)n * 2500 + rr * 50 + cc) * 32 + c32] = 0u;
    }
  }
  grid.sync();

  // ---- S2: ke2 (blocks 0..95, 128 co-slots, write <112) ----
  if (bid < 96) {
    int n = bid / 48, y = bid % 48;
    const unsigned short* src = k1_t + ((size_t)n * 50 + y) * 50 * 64;
    for (int f = t; f < 1200; f += 256) {
      int g = f >> 3, ci0 = (f & 7) * 8;
      int cc = g % 50, rr = g / 50;
      bf16x8 vv = *(const bf16x8*)&src[(rr * 50 + cc) * 64 + ci0];
      int ba = (((rr * 50 + cc) * 64 + ci0) * 2) ^ ((cc & 7) << 4);
      *(bf16x8*)((char*)sh + ba) = vv;
    }
    __syncthreads();
    int wid = t >> 6, l = t & 63, l15 = l & 15, lg = l >> 4;
    f32x4 acc[2][3];
#pragma unroll
    for (int mi = 0; mi < 2; ++mi)
#pragma unroll
      for (int nt = 0; nt < 3; ++nt) acc[mi][nt] = (f32x4){0.f, 0.f, 0.f, 0.f};
#pragma unroll
    for (int kbi = 0; kbi < 18; ++kbi) {
      int tap = kbi >> 1;
      int ky = tap / 3, kx = tap % 3;
      int ci0 = (kbi & 1) * 32 + lg * 8;
      bf16x8 afr[2];
#pragma unroll
      for (int mi = 0; mi < 2; ++mi)
        afr[mi] = *(const bf16x8*)&wt2[(size_t)((wid * 2 + mi) * 16 + l15) * 576 + kbi * 32 + lg * 8];
#pragma unroll
      for (int nt = 0; nt < 3; ++nt) {
        int col = nt * 16 + l15 + kx;
        int ba = (((ky * 50 + col) * 64 + ci0) * 2) ^ ((col & 7) << 4);
        bf16x8 bfr = *(const bf16x8*)((char*)sh + ba);
        acc[0][nt] = __builtin_amdgcn_mfma_f32_16x16x32_bf16(afr[0], bfr, acc[0][nt], 0, 0, 0);
        acc[1][nt] = __builtin_amdgcn_mfma_f32_16x16x32_bf16(afr[1], bfr, acc[1][nt], 0, 0, 0);
      }
    }
#pragma unroll
    for (int mi = 0; mi < 2; ++mi) {
      int co0 = (wid * 2 + mi) * 16 + lg * 4;
      if (co0 < 112) {
#pragma unroll
        for (int nt = 0; nt < 3; ++nt) {
          int px = nt * 16 + l15;
          float4 vv = {acc[mi][nt][0], acc[mi][nt][1], acc[mi][nt][2], acc[mi][nt][3]};
          *(float4*)&kern_t[((size_t)n * 2304 + y * 48 + px) * 112 + co0] = vv;
        }
      }
    }
  }
}

// ============ K_fused v7: w9-in-kernel + round-4 barrier-separated chunks ==========
__global__ __launch_bounds__(512, 4) void k_fused(
    const float* __restrict__ x, const float* __restrict__ kern_t,
    const unsigned short* __restrict__ pwb,
    const float* __restrict__ g2, const float* __restrict__ b2,
    const float* __restrict__ m2, const float* __restrict__ v2,
    float* __restrict__ out) {
  __shared__ __align__(16) char smem[76800];
  float* xls  = (float*)smem;                          // 8960 f  (35840 B)
  float* w9s  = (float*)(smem + 35840);                // 1152 f  (4608 B)
  float* sb2s = (float*)(smem + 40448);                // 512 f   (2048 B)
  unsigned short* finT = (unsigned short*)(smem + 44032); // 64 px x 256 ci (32768 B)
  float* ks   = (float*)(smem + 44032);                // 3360 f alias (dead before finT)

  int blk = blockIdx.x;                                // 576 = 2 * 48 * 6
  int n = blk / 288, r = blk % 288;
  int y48 = r / 6, xt = r % 6;
  int X0 = xt * 32, x480 = xt * 8;
  int t = threadIdx.x;

  if (t < 256) {
    float iv = g2[t] / sqrtf(v2[t] + EPSB);
    sb2s[t] = iv; sb2s[256 + t] = b2[t] - m2[t] * iv;
  }
  for (int f = t; f < 840; f += 512) {                 // stage kern_t window 3x10x112
    int slot = f / 280, rem = f % 280;
    int cx = rem / 28, c4 = rem % 28;
    int sy = min(max(y48 + slot - 1, 0), 47);
    int sx = min(max(x480 + cx - 1, 0), 47);
    float4 vv = *(const float4*)&kern_t[((size_t)n * 2304 + sy * 48 + sx) * 112 + c4 * 4];
    *(float4*)&ks[(slot * 10 + cx) * 112 + c4 * 4] = vv;
  }
  const float* xb = x + (size_t)n * 256 * 2304;
  for (int f = t; f < 8448; f += 512) {                // stage x window
    int c = f / 33, rc = f - c * 33;
    int ry = rc / 11, cx = rc - ry * 11;
    int sy = min(max(y48 + ry - 1, 0), 47);
    int sx = min(max(x480 + cx - 1, 0), 47);
    int slot = (c & 3) * 64 + (c >> 2);
    xls[slot * 35 + rc] = xb[(size_t)c * 2304 + sy * 48 + sx];
  }
  __syncthreads();

  // ---- softmax + bilinear + fold -> w9s (4 lanes per output triple) ----
  {
    int s = t & 3, tri = t >> 2;                       // 128 triples
    int u = tri & 3, w2l = (tri >> 2) & 15, yhh = tri >> 6;
    int y96 = 2 * y48 + yhh;
    int w2 = xt * 16 + w2l;
    float syf = fminf(fmaxf(y96 * 0.5f - 0.25f, 0.f), 47.f);
    int y0 = (int)syf; float wy = syf - (float)y0; int y1 = min(y0 + 1, 47);
    float sxf = fminf(fmaxf(w2 * 0.5f - 0.25f, 0.f), 47.f);
    int x0 = (int)sxf; float wx = sxf - (float)x0; int x1 = min(x0 + 1, 47);
    int slr = ((s & 2) ? y1 : y0) - y48 + 1;
    int cxr = ((s & 1) ? x1 : x0) - x480 + 1;
    float wgt = ((s & 1) ? wx : 1.f - wx) * ((s & 2) ? wy : 1.f - wy);
    const float* p = &ks[(slr * 10 + cxr) * 112 + u * 25];
    float bl[25], mx = -3.4e38f;
#pragma unroll
    for (int k = 0; k < 25; ++k) { bl[k] = p[k]; mx = fmaxf(mx, bl[k]); }
    float sum = 0.f;
#pragma unroll
    for (int k = 0; k < 25; ++k) { bl[k] = __expf(bl[k] - mx); sum += bl[k]; }
    float rs = wgt / sum;
#pragma unroll
    for (int k = 0; k < 25; ++k) {
      bl[k] *= rs;
      bl[k] += __shfl_xor(bl[k], 1);
      bl[k] += __shfl_xor(bl[k], 2);
    }
    if (s == 0) {
#pragma unroll
      for (int kh = 0; kh < 5; ++kh) {
        bool vy = (unsigned)(y96 + kh - 2) < 96u;
#pragma unroll
        for (int kw = 0; kw < 5; ++kw) {
          bool vx = (unsigned)(w2 + kw - 2) < 96u;
          if (!(vy && vx)) bl[kh * 5 + kw] = 0.f;
        }
      }
      int py = yhh, px_ = w2l & 1;
      float cc0[5], cc1[5], cc2[5];
#pragma unroll
      for (int kh = 0; kh < 5; ++kh) {
        cc0[kh] = px_ ? bl[kh * 5 + 0] : bl[kh * 5 + 0] + bl[kh * 5 + 1];
        cc1[kh] = px_ ? bl[kh * 5 + 1] + bl[kh * 5 + 2] : bl[kh * 5 + 2] + bl[kh * 5 + 3];
        cc2[kh] = px_ ? bl[kh * 5 + 3] + bl[kh * 5 + 4] : bl[kh * 5 + 4];
      }
      float* op = &w9s[(yhh * 16 + w2l) * 36 + u * 9];
      op[0] = py ? cc0[0] : cc0[0] + cc0[1];
      op[1] = py ? cc1[0] : cc1[0] + cc1[1];
      op[2] = py ? cc2[0] : cc2[0] + cc2[1];
      op[3] = py ? cc0[1] + cc0[2] : cc0[2] + cc0[3];
      op[4] = py ? cc1[1] + cc1[2] : cc1[2] + cc1[3];
      op[5] = py ? cc2[1] + cc2[2] : cc2[2] + cc2[3];
      op[6] = py ? cc0[3] + cc0[4] : cc0[4];
      op[7] = py ? cc1[3] + cc1[4] : cc1[4];
      op[8] = py ? cc2[3] + cc2[4] : cc2[4];
    }
  }
  __syncthreads();                                     // w9s ready; ks dead

  int ci = t & 255, rY = t >> 8;
  int u = ci >> 6, ch = ci & 63;
  int cb = ci >> 3, crr = ci & 7;
  int wid = t >> 6, l = t & 63, l15 = l & 15, lg = l >> 4;
  const unsigned short* a0p = pwb + (size_t)(wid * 32 + l15) * 256;
  const unsigned short* a1p = a0p + 16 * 256;
  size_t outn = (size_t)n * 256 * 36864;
  int Ybase = 4 * y48;

#pragma unroll
  for (int c = 0; c < 2; ++c) {
    // ---- phase 1: 9-tap reassembly for 2 Y rows x 32 X -> finT ----
    {
      const float* xc0 = &xls[((rY * 2 + 0) * 64 + ch) * 35];
      const float* xc1 = &xls[((rY * 2 + 1) * 64 + ch) * 35];
      float xw0[9], xw1[9];
#pragma unroll
      for (int ry = 0; ry < 3; ++ry)
#pragma unroll
        for (int cx = 0; cx < 3; ++cx) {
          xw0[ry * 3 + cx] = xc0[ry * 11 + cx];
          xw1[ry * 3 + cx] = xc1[ry * 11 + cx];
        }
#pragma unroll
      for (int j = 0; j < 16; ++j) {
        if (j >= 2 && (j & 1) == 0) {
          int nc = (j >> 1) + 2;
#pragma unroll
          for (int ry = 0; ry < 3; ++ry) {
            xw0[ry*3+0]=xw0[ry*3+1]; xw0[ry*3+1]=xw0[ry*3+2]; xw0[ry*3+2]=xc0[ry*11+nc];
            xw1[ry*3+0]=xw1[ry*3+1]; xw1[ry*3+1]=xw1[ry*3+2]; xw1[ry*3+2]=xc1[ry*11+nc];
          }
        }
        const float* wt = &w9s[(c * 16 + j) * 36 + u * 9];
        float a0 = 0.f, a1 = 0.f;
#pragma unroll
        for (int k9 = 0; k9 < 9; ++k9) {
          float wv = wt[k9];
          a0 = fmaf(xw0[k9], wv, a0);
          a1 = fmaf(xw1[k9], wv, a1);
        }
        int px0 = rY * 32 + 2 * j, px1 = px0 + 1;
        finT[px0 * 256 + ((cb ^ (px0 & 7)) * 8 + crr)] = f2b(a0);
        finT[px1 * 256 + ((cb ^ (px1 & 7)) * 8 + crr)] = f2b(a1);
      }
    }
    __syncthreads();

    // ---- phase 2: MFMA  C[256 o][64 px] = pwb @ finT ----
    f32x4 acc[2][4];
#pragma unroll
    for (int mi = 0; mi < 2; ++mi)
#pragma unroll
      for (int nt = 0; nt < 4; ++nt) acc[mi][nt] = (f32x4){0.f, 0.f, 0.f, 0.f};
#pragma unroll
    for (int kbi = 0; kbi < 8; ++kbi) {
      bf16x8 afr0 = *(const bf16x8*)&a0p[kbi * 32 + lg * 8];
      bf16x8 afr1 = *(const bf16x8*)&a1p[kbi * 32 + lg * 8];
      int cbk = kbi * 4 + lg;
#pragma unroll
      for (int nt = 0; nt < 4; ++nt) {
        int row = nt * 16 + l15;
        bf16x8 bfr = *(const bf16x8*)&finT[row * 256 + ((cbk ^ (row & 7)) * 8)];
        acc[0][nt] = __builtin_amdgcn_mfma_f32_16x16x32_bf16(afr0, bfr, acc[0][nt], 0, 0, 0);
        acc[1][nt] = __builtin_amdgcn_mfma_f32_16x16x32_bf16(afr1, bfr, acc[1][nt], 0, 0, 0);
      }
    }
#pragma unroll
    for (int mi = 0; mi < 2; ++mi) {
#pragma unroll
      for (int r4 = 0; r4 < 4; ++r4) {
        int o = (wid * 2 + mi) * 16 + lg * 4 + r4;
        float sc = sb2s[o], bi = sb2s[256 + o];
#pragma unroll
        for (int nt = 0; nt < 4; ++nt) {
          int px = nt * 16 + l15;
          int Yl = c * 2 + (px >> 5), Xl = px & 31;
          float val = fmaxf(fmaf(acc[mi][nt][r4], sc, bi), 0.f);
          out[outn + (size_t)o * 36864 + (size_t)(Ybase + Yl) * 192 + X0 + Xl] = val;
        }
      }
    }
    if (c == 0) __syncthreads();   // protect finT before next chunk's phase 1
  }
}

extern "C" void kernel_launch(void* const* d_in, const int* in_sizes, int n_in,
                              void* d_out, int out_size, void* d_ws, size_t ws_size,
                              hipStream_t stream) {
  const float* x   = (const float*)d_in[0];
  const float* cw  = (const float*)d_in[1];
  const float* g1  = (const float*)d_in[2];
  const float* b1  = (const float*)d_in[3];
  const float* m1  = (const float*)d_in[4];
  const float* v1  = (const float*)d_in[5];
  const float* k1w = (const float*)d_in[6];
  const float* gk  = (const float*)d_in[7];
  const float* bk  = (const float*)d_in[8];
  const float* mk  = (const float*)d_in[9];
  const float* vk  = (const float*)d_in[10];
  const float* k2w = (const float*)d_in[11];
  const float* pw  = (const float*)d_in[12];
  const float* g2  = (const float*)d_in[13];
  const float* b2  = (const float*)d_in[14];
  const float* m2  = (const float*)d_in[15];
  const float* v2  = (const float*)d_in[16];
  float* out = (float*)d_out;
  float* ws  = (float*)d_ws;

  unsigned short* comp_t = (unsigned short*)ws;            // 346112 bf16
  unsigned short* k1_t   = (unsigned short*)(ws + 173056); // 320000 bf16
  float* kern_t = ws + 333056;                             // 516096 f32
  unsigned short* pwb = (unsigned short*)(ws + 849152);    // 65536 bf16
  unsigned short* wt1 = (unsigned short*)(ws + 881920);    // 36864 bf16
  unsigned short* wt2 = (unsigned short*)(ws + 900352);    // 73728 bf16

  void* args[] = {
    (void*)&x, (void*)&cw, (void*)&g1, (void*)&b1, (void*)&m1, (void*)&v1,
    (void*)&k1w, (void*)&gk, (void*)&bk, (void*)&mk, (void*)&vk,
    (void*)&k2w, (void*)&pw,
    (void*)&comp_t, (void*)&k1_t, (void*)&kern_t,
    (void*)&pwb, (void*)&wt1, (void*)&wt2
  };
  hipLaunchCooperativeKernel((const void*)k_pred, dim3(256), dim3(256), args, 0, stream);

  k_fused<<<576, 512, 0, stream>>>(x, kern_t, pwb, g2, b2, m2, v2, out);
}

// Round 8
// 185.943 us; speedup vs baseline: 1.5486x; 1.5486x over previous
//
#include <hip/hip_runtime.h>

#define EPSB 1e-5f

typedef __attribute__((ext_vector_type(8))) short bf16x8;
typedef __attribute__((ext_vector_type(4))) float f32x4;

__device__ __forceinline__ unsigned short f2b(float f) {
  union { float f; unsigned u; } cv; cv.f = f;
  unsigned r = cv.u + 0x7FFFu + ((cv.u >> 16) & 1u);
  return (unsigned short)(r >> 16);
}

// ============ K1: MFMA compress (+BN+ReLU) | weight conversions | border zeros ======
// blocks 0..95: per (n,y) row GEMM comp[64 co][48 px] = W[64x256] @ X[256][48]
// blocks 96+ : pwb/wt1/wt2 conversions + comp_t/k1_t border zeros
__global__ __launch_bounds__(256) void k_compress(
    const float* __restrict__ x, const float* __restrict__ cw,
    const float* __restrict__ g1, const float* __restrict__ b1,
    const float* __restrict__ m1, const float* __restrict__ v1,
    const float* __restrict__ k1w, const float* __restrict__ k2w,
    const float* __restrict__ pw,
    unsigned short* __restrict__ comp_t, unsigned short* __restrict__ k1_t,
    unsigned short* __restrict__ pwb, unsigned short* __restrict__ wt1,
    unsigned short* __restrict__ wt2) {
  int bid = blockIdx.x, t = threadIdx.x;
  if (bid >= 96) {
    int u = (bid - 96) * 256 + t;
    if (u < 65536) {
      pwb[u] = f2b(pw[u]);
    } else if (u < 102400) {
      int a = u - 65536;
      int co = a / 576, k = a % 576, tap = k >> 6, ci = k & 63;
      wt1[a] = f2b(k1w[co * 576 + ci * 9 + tap]);
    } else if (u < 176128) {
      int c2 = u - 102400;
      int co = c2 / 576, k = c2 % 576, tap = k >> 6, ci = k & 63;
      wt2[c2] = (co < 100) ? f2b(k2w[co * 576 + ci * 9 + tap]) : (unsigned short)0;
    } else {
      int v = u - 176128;
      if (v < 25600) {
        int n = v / 12800, r = v % 12800;
        int bp = r >> 5, c32 = r & 31;
        int rr, cc;
        if (bp < 104) { rr = bp / 52; cc = bp % 52; }
        else if (bp >= 296) { rr = 50 + (bp - 296) / 52; cc = (bp - 296) % 52; }
        else { int q = bp - 104; rr = 2 + (q >> 2); int c4 = q & 3; cc = (c4 < 2) ? c4 : c4 + 48; }
        ((unsigned*)comp_t)[((size_t)n * 2704 + rr * 52 + cc) * 32 + c32] = 0u;
      } else if (v < 38144) {
        int j = v - 25600;
        int n = j / 6272, r = j % 6272;
        int bp = r >> 5, c32 = r & 31;
        int rr, cc;
        if (bp < 50) { rr = 0; cc = bp; }
        else if (bp >= 146) { rr = 49; cc = bp - 146; }
        else { int q = bp - 50; rr = 1 + (q >> 1); cc = (q & 1) * 49; }
        ((unsigned*)k1_t)[((size_t)n * 2500 + rr * 50 + cc) * 32 + c32] = 0u;
      }
    }
    return;
  }
  // ---- MFMA compress ----
  __shared__ __align__(16) unsigned short wlds[16384];   // W [co][256 ci], XOR by co
  __shared__ __align__(16) unsigned short xlds[12288];   // X [px][256 ci], XOR by px
  int n = bid / 48, y = bid % 48;
  for (int f = t; f < 16384; f += 256) {                 // cw[co][ci] coalesced
    int co = f >> 8, ci = f & 255;
    int ba = (f * 2) ^ ((co & 7) << 4);
    *(unsigned short*)((char*)wlds + ba) = f2b(cw[f]);
  }
  const float* xrow = x + (size_t)n * 256 * 2304 + y * 48;
  for (int f = t; f < 12288; f += 256) {                 // x row coalesced (48/ci)
    int ci = f / 48, px = f - ci * 48;
    int ba = ((px * 256 + ci) * 2) ^ ((px & 7) << 4);
    *(unsigned short*)((char*)xlds + ba) = f2b(xrow[(size_t)ci * 2304 + px]);
  }
  __syncthreads();
  int wid = t >> 6, l = t & 63, l15 = l & 15, lg = l >> 4;
  f32x4 acc[3];
  acc[0] = acc[1] = acc[2] = (f32x4){0.f, 0.f, 0.f, 0.f};
  int coA = wid * 16 + l15;
#pragma unroll
  for (int kbi = 0; kbi < 8; ++kbi) {
    int col = kbi * 32 + lg * 8;
    bf16x8 afr = *(const bf16x8*)((char*)wlds + (((coA * 256 + col) * 2) ^ ((coA & 7) << 4)));
#pragma unroll
    for (int nt = 0; nt < 3; ++nt) {
      int px = nt * 16 + l15;
      bf16x8 bfr = *(const bf16x8*)((char*)xlds + (((px * 256 + col) * 2) ^ ((px & 7) << 4)));
      acc[nt] = __builtin_amdgcn_mfma_f32_16x16x32_bf16(afr, bfr, acc[nt], 0, 0, 0);
    }
  }
  int co0 = wid * 16 + lg * 4;
  float s0 = g1[co0] / sqrtf(v1[co0] + EPSB);
  float s1 = g1[co0 + 1] / sqrtf(v1[co0 + 1] + EPSB);
  float s2 = g1[co0 + 2] / sqrtf(v1[co0 + 2] + EPSB);
  float s3 = g1[co0 + 3] / sqrtf(v1[co0 + 3] + EPSB);
  float d0 = b1[co0] - m1[co0] * s0;
  float d1 = b1[co0 + 1] - m1[co0 + 1] * s1;
  float d2 = b1[co0 + 2] - m1[co0 + 2] * s2;
  float d3 = b1[co0 + 3] - m1[co0 + 3] * s3;
  unsigned short* dst = comp_t + ((size_t)n * 2704 + (y + 2) * 52) * 64;
#pragma unroll
  for (int nt = 0; nt < 3; ++nt) {
    int px = nt * 16 + l15;
    ushort4 pk;
    pk.x = f2b(fmaxf(fmaf(acc[nt][0], s0, d0), 0.f));
    pk.y = f2b(fmaxf(fmaf(acc[nt][1], s1, d1), 0.f));
    pk.z = f2b(fmaxf(fmaf(acc[nt][2], s2, d2), 0.f));
    pk.w = f2b(fmaxf(fmaf(acc[nt][3], s3, d3), 0.f));
    *(ushort4*)&dst[(px + 2) * 64 + co0] = pk;
  }
}

// ============ K2: 3x3 dil=2 conv via MFMA + BN + ReLU ===============================
__global__ __launch_bounds__(128) void k_ke1(
    const unsigned short* __restrict__ comp_t, const unsigned short* __restrict__ wt1,
    const float* __restrict__ gk, const float* __restrict__ bk,
    const float* __restrict__ mk, const float* __restrict__ vk,
    unsigned short* __restrict__ k1_t) {
  __shared__ unsigned short sA[16640];       // 5 rows x 52 cols x 64 ci, XOR by col
  int bid = blockIdx.x, t = threadIdx.x;
  int n = bid / 96, rem = bid % 96;
  int y = rem >> 1, coh = rem & 1;
  const unsigned short* src = comp_t + ((size_t)n * 52 + y) * 52 * 64;
  for (int f = t; f < 2080; f += 128) {
    int g = f >> 3, ci0 = (f & 7) * 8;
    int cc = g % 52, rr = g / 52;
    bf16x8 vv = *(const bf16x8*)&src[(rr * 52 + cc) * 64 + ci0];
    int ba = (((rr * 52 + cc) * 64 + ci0) * 2) ^ ((cc & 7) << 4);
    *(bf16x8*)((char*)sA + ba) = vv;
  }
  __syncthreads();
  int wid = t >> 6, l = t & 63, l15 = l & 15, lg = l >> 4;
  f32x4 acc[3];
  acc[0] = acc[1] = acc[2] = (f32x4){0.f, 0.f, 0.f, 0.f};
  const unsigned short* arow = wt1 + (size_t)(coh * 32 + wid * 16 + l15) * 576;
#pragma unroll
  for (int kbi = 0; kbi < 18; ++kbi) {
    int tap = kbi >> 1;
    int ky = tap / 3, kx = tap % 3;
    int ci0 = (kbi & 1) * 32 + lg * 8;
    bf16x8 afr = *(const bf16x8*)&arow[kbi * 32 + lg * 8];
#pragma unroll
    for (int nt = 0; nt < 3; ++nt) {
      int col = nt * 16 + l15 + 2 * kx;
      int ba = (((2 * ky * 52 + col) * 64 + ci0) * 2) ^ ((col & 7) << 4);
      bf16x8 bfr = *(const bf16x8*)((char*)sA + ba);
      acc[nt] = __builtin_amdgcn_mfma_f32_16x16x32_bf16(afr, bfr, acc[nt], 0, 0, 0);
    }
  }
  unsigned short* dst = k1_t + ((size_t)n * 50 + (y + 1)) * 50 * 64;
  int co0 = coh * 32 + wid * 16 + lg * 4;
  float s0 = gk[co0] / sqrtf(vk[co0] + EPSB);
  float s1 = gk[co0 + 1] / sqrtf(vk[co0 + 1] + EPSB);
  float s2 = gk[co0 + 2] / sqrtf(vk[co0 + 2] + EPSB);
  float s3 = gk[co0 + 3] / sqrtf(vk[co0 + 3] + EPSB);
  float d0 = bk[co0] - mk[co0] * s0;
  float d1 = bk[co0 + 1] - mk[co0 + 1] * s1;
  float d2 = bk[co0 + 2] - mk[co0 + 2] * s2;
  float d3 = bk[co0 + 3] - mk[co0 + 3] * s3;
#pragma unroll
  for (int nt = 0; nt < 3; ++nt) {
    int px = nt * 16 + l15;
    ushort4 pk;
    pk.x = f2b(fmaxf(fmaf(acc[nt][0], s0, d0), 0.f));
    pk.y = f2b(fmaxf(fmaf(acc[nt][1], s1, d1), 0.f));
    pk.z = f2b(fmaxf(fmaf(acc[nt][2], s2, d2), 0.f));
    pk.w = f2b(fmaxf(fmaf(acc[nt][3], s3, d3), 0.f));
    *(ushort4*)&dst[(px + 1) * 64 + co0] = pk;
  }
}

// ============ K3: 3x3 conv via MFMA -> kern_t[n][pix][112] fp32 =====================
__global__ __launch_bounds__(128) void k_ke2(
    const unsigned short* __restrict__ k1_t, const unsigned short* __restrict__ wt2,
    float* __restrict__ kern_t) {
  __shared__ unsigned short sA[9600];        // 3 rows x 50 cols x 64 ci
  int bid = blockIdx.x, t = threadIdx.x;
  int n = bid / 96, rem = bid % 96;
  int y = rem >> 1, coh = rem & 1;
  const unsigned short* src = k1_t + ((size_t)n * 50 + y) * 50 * 64;
  for (int f = t; f < 1200; f += 128) {
    int g = f >> 3, ci0 = (f & 7) * 8;
    int cc = g % 50, rr = g / 50;
    bf16x8 vv = *(const bf16x8*)&src[(rr * 50 + cc) * 64 + ci0];
    int ba = (((rr * 50 + cc) * 64 + ci0) * 2) ^ ((cc & 7) << 4);
    *(bf16x8*)((char*)sA + ba) = vv;
  }
  __syncthreads();
  int wid = t >> 6, l = t & 63, l15 = l & 15, lg = l >> 4;
  f32x4 acc[2][3];
#pragma unroll
  for (int mi = 0; mi < 2; ++mi)
#pragma unroll
    for (int nt = 0; nt < 3; ++nt) acc[mi][nt] = (f32x4){0.f, 0.f, 0.f, 0.f};
#pragma unroll
  for (int kbi = 0; kbi < 18; ++kbi) {
    int tap = kbi >> 1;
    int ky = tap / 3, kx = tap % 3;
    int ci0 = (kbi & 1) * 32 + lg * 8;
    bf16x8 afr[2];
#pragma unroll
    for (int mi = 0; mi < 2; ++mi)
      afr[mi] = *(const bf16x8*)&wt2[(size_t)(coh * 64 + (wid * 2 + mi) * 16 + l15) * 576 + kbi * 32 + lg * 8];
#pragma unroll
    for (int nt = 0; nt < 3; ++nt) {
      int col = nt * 16 + l15 + kx;
      int ba = (((ky * 50 + col) * 64 + ci0) * 2) ^ ((col & 7) << 4);
      bf16x8 bfr = *(const bf16x8*)((char*)sA + ba);
      acc[0][nt] = __builtin_amdgcn_mfma_f32_16x16x32_bf16(afr[0], bfr, acc[0][nt], 0, 0, 0);
      acc[1][nt] = __builtin_amdgcn_mfma_f32_16x16x32_bf16(afr[1], bfr, acc[1][nt], 0, 0, 0);
    }
  }
#pragma unroll
  for (int mi = 0; mi < 2; ++mi) {
    int co0 = coh * 64 + (wid * 2 + mi) * 16 + lg * 4;
    if (co0 < 112) {
#pragma unroll
      for (int nt = 0; nt < 3; ++nt) {
        int px = nt * 16 + l15;
        float4 vv = {acc[mi][nt][0], acc[mi][nt][1], acc[mi][nt][2], acc[mi][nt][3]};
        *(float4*)&kern_t[((size_t)n * 2304 + y * 48 + px) * 112 + co0] = vv;
      }
    }
  }
}

// ============ K4: fused softmax/bilinear/fold + reassembly + MFMA proj + BN + ReLU ==
__global__ __launch_bounds__(512, 4) void k_fused(
    const float* __restrict__ x, const float* __restrict__ kern_t,
    const unsigned short* __restrict__ pwb,
    const float* __restrict__ g2, const float* __restrict__ b2,
    const float* __restrict__ m2, const float* __restrict__ v2,
    float* __restrict__ out) {
  __shared__ __align__(16) char smem[76800];
  float* xls  = (float*)smem;                          // 8960 f  (35840 B)
  float* w9s  = (float*)(smem + 35840);                // 1152 f  (4608 B)
  float* sb2s = (float*)(smem + 40448);                // 512 f   (2048 B)
  unsigned short* finT = (unsigned short*)(smem + 44032); // 64 px x 256 ci (32768 B)
  float* ks   = (float*)(smem + 44032);                // 3360 f alias (dead before finT)

  int blk = blockIdx.x;                                // 576 = 2 * 48 * 6
  int n = blk / 288, r = blk % 288;
  int y48 = r / 6, xt = r % 6;
  int X0 = xt * 32, x480 = xt * 8;
  int t = threadIdx.x;

  if (t < 256) {
    float iv = g2[t] / sqrtf(v2[t] + EPSB);
    sb2s[t] = iv; sb2s[256 + t] = b2[t] - m2[t] * iv;
  }
  for (int f = t; f < 840; f += 512) {                 // stage kern_t window 3x10x112
    int slot = f / 280, rem = f % 280;
    int cx = rem / 28, c4 = rem % 28;
    int sy = min(max(y48 + slot - 1, 0), 47);
    int sx = min(max(x480 + cx - 1, 0), 47);
    float4 vv = *(const float4*)&kern_t[((size_t)n * 2304 + sy * 48 + sx) * 112 + c4 * 4];
    *(float4*)&ks[(slot * 10 + cx) * 112 + c4 * 4] = vv;
  }
  const float* xb = x + (size_t)n * 256 * 2304;
  for (int f = t; f < 8448; f += 512) {                // stage x window
    int c = f / 33, rc = f - c * 33;
    int ry = rc / 11, cx = rc - ry * 11;
    int sy = min(max(y48 + ry - 1, 0), 47);
    int sx = min(max(x480 + cx - 1, 0), 47);
    int slot = (c & 3) * 64 + (c >> 2);
    xls[slot * 35 + rc] = xb[(size_t)c * 2304 + sy * 48 + sx];
  }
  __syncthreads();

  // ---- softmax + bilinear + fold -> w9s (4 lanes per output triple) ----
  {
    int s = t & 3, tri = t >> 2;                       // 128 triples
    int u = tri & 3, w2l = (tri >> 2) & 15, yhh = tri >> 6;
    int y96 = 2 * y48 + yhh;
    int w2 = xt * 16 + w2l;
    float syf = fminf(fmaxf(y96 * 0.5f - 0.25f, 0.f), 47.f);
    int y0 = (int)syf; float wy = syf - (float)y0; int y1 = min(y0 + 1, 47);
    float sxf = fminf(fmaxf(w2 * 0.5f - 0.25f, 0.f), 47.f);
    int x0 = (int)sxf; float wx = sxf - (float)x0; int x1 = min(x0 + 1, 47);
    int slr = ((s & 2) ? y1 : y0) - y48 + 1;
    int cxr = ((s & 1) ? x1 : x0) - x480 + 1;
    float wgt = ((s & 1) ? wx : 1.f - wx) * ((s & 2) ? wy : 1.f - wy);
    const float* p = &ks[(slr * 10 + cxr) * 112 + u * 25];
    float bl[25], mx = -3.4e38f;
#pragma unroll
    for (int k = 0; k < 25; ++k) { bl[k] = p[k]; mx = fmaxf(mx, bl[k]); }
    float sum = 0.f;
#pragma unroll
    for (int k = 0; k < 25; ++k) { bl[k] = __expf(bl[k] - mx); sum += bl[k]; }
    float rs = wgt / sum;
#pragma unroll
    for (int k = 0; k < 25; ++k) {
      bl[k] *= rs;
      bl[k] += __shfl_xor(bl[k], 1);
      bl[k] += __shfl_xor(bl[k], 2);
    }
    if (s == 0) {
#pragma unroll
      for (int kh = 0; kh < 5; ++kh) {
        bool vy = (unsigned)(y96 + kh - 2) < 96u;
#pragma unroll
        for (int kw = 0; kw < 5; ++kw) {
          bool vx = (unsigned)(w2 + kw - 2) < 96u;
          if (!(vy && vx)) bl[kh * 5 + kw] = 0.f;
        }
      }
      int py = yhh, px_ = w2l & 1;
      float cc0[5], cc1[5], cc2[5];
#pragma unroll
      for (int kh = 0; kh < 5; ++kh) {
        cc0[kh] = px_ ? bl[kh * 5 + 0] : bl[kh * 5 + 0] + bl[kh * 5 + 1];
        cc1[kh] = px_ ? bl[kh * 5 + 1] + bl[kh * 5 + 2] : bl[kh * 5 + 2] + bl[kh * 5 + 3];
        cc2[kh] = px_ ? bl[kh * 5 + 3] + bl[kh * 5 + 4] : bl[kh * 5 + 4];
      }
      float* op = &w9s[(yhh * 16 + w2l) * 36 + u * 9];
      op[0] = py ? cc0[0] : cc0[0] + cc0[1];
      op[1] = py ? cc1[0] : cc1[0] + cc1[1];
      op[2] = py ? cc2[0] : cc2[0] + cc2[1];
      op[3] = py ? cc0[1] + cc0[2] : cc0[2] + cc0[3];
      op[4] = py ? cc1[1] + cc1[2] : cc1[2] + cc1[3];
      op[5] = py ? cc2[1] + cc2[2] : cc2[2] + cc2[3];
      op[6] = py ? cc0[3] + cc0[4] : cc0[4];
      op[7] = py ? cc1[3] + cc1[4] : cc1[4];
      op[8] = py ? cc2[3] + cc2[4] : cc2[4];
    }
  }
  __syncthreads();                                     // w9s ready; ks dead

  int ci = t & 255, rY = t >> 8;
  int u = ci >> 6, ch = ci & 63;
  int cb = ci >> 3, crr = ci & 7;
  int wid = t >> 6, l = t & 63, l15 = l & 15, lg = l >> 4;
  const unsigned short* a0p = pwb + (size_t)(wid * 32 + l15) * 256;
  const unsigned short* a1p = a0p + 16 * 256;
  size_t outn = (size_t)n * 256 * 36864;
  int Ybase = 4 * y48;

#pragma unroll
  for (int c = 0; c < 2; ++c) {
    // ---- phase 1: 9-tap reassembly for 2 Y rows x 32 X -> finT ----
    {
      const float* xc0 = &xls[((rY * 2 + 0) * 64 + ch) * 35];
      const float* xc1 = &xls[((rY * 2 + 1) * 64 + ch) * 35];
      float xw0[9], xw1[9];
#pragma unroll
      for (int ry = 0; ry < 3; ++ry)
#pragma unroll
        for (int cx = 0; cx < 3; ++cx) {
          xw0[ry * 3 + cx] = xc0[ry * 11 + cx];
          xw1[ry * 3 + cx] = xc1[ry * 11 + cx];
        }
#pragma unroll
      for (int j = 0; j < 16; ++j) {
        if (j >= 2 && (j & 1) == 0) {
          int nc = (j >> 1) + 2;
#pragma unroll
          for (int ry = 0; ry < 3; ++ry) {
            xw0[ry*3+0]=xw0[ry*3+1]; xw0[ry*3+1]=xw0[ry*3+2]; xw0[ry*3+2]=xc0[ry*11+nc];
            xw1[ry*3+0]=xw1[ry*3+1]; xw1[ry*3+1]=xw1[ry*3+2]; xw1[ry*3+2]=xc1[ry*11+nc];
          }
        }
        const float* wt = &w9s[(c * 16 + j) * 36 + u * 9];
        float a0 = 0.f, a1 = 0.f;
#pragma unroll
        for (int k9 = 0; k9 < 9; ++k9) {
          float wv = wt[k9];
          a0 = fmaf(xw0[k9], wv, a0);
          a1 = fmaf(xw1[k9], wv, a1);
        }
        int px0 = rY * 32 + 2 * j, px1 = px0 + 1;
        finT[px0 * 256 + ((cb ^ (px0 & 7)) * 8 + crr)] = f2b(a0);
        finT[px1 * 256 + ((cb ^ (px1 & 7)) * 8 + crr)] = f2b(a1);
      }
    }
    __syncthreads();

    // ---- phase 2: MFMA  C[256 o][64 px] = pwb @ finT ----
    f32x4 acc[2][4];
#pragma unroll
    for (int mi = 0; mi < 2; ++mi)
#pragma unroll
      for (int nt = 0; nt < 4; ++nt) acc[mi][nt] = (f32x4){0.f, 0.f, 0.f, 0.f};
#pragma unroll
    for (int kbi = 0; kbi < 8; ++kbi) {
      bf16x8 afr0 = *(const bf16x8*)&a0p[kbi * 32 + lg * 8];
      bf16x8 afr1 = *(const bf16x8*)&a1p[kbi * 32 + lg * 8];
      int cbk = kbi * 4 + lg;
#pragma unroll
      for (int nt = 0; nt < 4; ++nt) {
        int row = nt * 16 + l15;
        bf16x8 bfr = *(const bf16x8*)&finT[row * 256 + ((cbk ^ (row & 7)) * 8)];
        acc[0][nt] = __builtin_amdgcn_mfma_f32_16x16x32_bf16(afr0, bfr, acc[0][nt], 0, 0, 0);
        acc[1][nt] = __builtin_amdgcn_mfma_f32_16x16x32_bf16(afr1, bfr, acc[1][nt], 0, 0, 0);
      }
    }
#pragma unroll
    for (int mi = 0; mi < 2; ++mi) {
#pragma unroll
      for (int r4 = 0; r4 < 4; ++r4) {
        int o = (wid * 2 + mi) * 16 + lg * 4 + r4;
        float sc = sb2s[o], bi = sb2s[256 + o];
#pragma unroll
        for (int nt = 0; nt < 4; ++nt) {
          int px = nt * 16 + l15;
          int Yl = c * 2 + (px >> 5), Xl = px & 31;
          float val = fmaxf(fmaf(acc[mi][nt][r4], sc, bi), 0.f);
          out[outn + (size_t)o * 36864 + (size_t)(Ybase + Yl) * 192 + X0 + Xl] = val;
        }
      }
    }
    if (c == 0) __syncthreads();   // protect finT before next chunk's phase 1
  }
}

extern "C" void kernel_launch(void* const* d_in, const int* in_sizes, int n_in,
                              void* d_out, int out_size, void* d_ws, size_t ws_size,
                              hipStream_t stream) {
  const float* x   = (const float*)d_in[0];
  const float* cw  = (const float*)d_in[1];
  const float* g1  = (const float*)d_in[2];
  const float* b1  = (const float*)d_in[3];
  const float* m1  = (const float*)d_in[4];
  const float* v1  = (const float*)d_in[5];
  const float* k1w = (const float*)d_in[6];
  const float* gk  = (const float*)d_in[7];
  const float* bk  = (const float*)d_in[8];
  const float* mk  = (const float*)d_in[9];
  const float* vk  = (const float*)d_in[10];
  const float* k2w = (const float*)d_in[11];
  const float* pw  = (const float*)d_in[12];
  const float* g2  = (const float*)d_in[13];
  const float* b2  = (const float*)d_in[14];
  const float* m2  = (const float*)d_in[15];
  const float* v2  = (const float*)d_in[16];
  float* out = (float*)d_out;
  float* ws  = (float*)d_ws;

  unsigned short* comp_t = (unsigned short*)ws;            // 346112 bf16
  unsigned short* k1_t   = (unsigned short*)(ws + 173056); // 320000 bf16
  float* kern_t = ws + 333056;                             // 516096 f32
  unsigned short* pwb = (unsigned short*)(ws + 849152);    // 65536 bf16
  unsigned short* wt1 = (unsigned short*)(ws + 881920);    // 36864 bf16
  unsigned short* wt2 = (unsigned short*)(ws + 900352);    // 73728 bf16

  k_compress<<<933, 256, 0, stream>>>(x, cw, g1, b1, m1, v1, k1w, k2w, pw,
                                      comp_t, k1_t, pwb, wt1, wt2);
  k_ke1<<<192, 128, 0, stream>>>(comp_t, wt1, gk, bk, mk, vk, k1_t);
  k_ke2<<<192, 128, 0, stream>>>(k1_t, wt2, kern_t);
  k_fused<<<576, 512, 0, stream>>>(x, kern_t, pwb, g2, b2, m2, v2, out);
}